// Round 5
// baseline (449.896 us; speedup 1.0000x reference)
//
#include <hip/hip_runtime.h>
#include <hip/hip_bf16.h>

#define HDIM 4096
#define DHEAD 128
#define NQH 32
#define NKVH 8
#define SEQ 2048
#define QKVN 6144  // fused N = 4096 + 1024 + 1024

typedef __bf16 bf16x8 __attribute__((ext_vector_type(8)));
typedef unsigned short ushort8 __attribute__((ext_vector_type(8)));
typedef float f32x4 __attribute__((ext_vector_type(4)));

// wait until <= N vector-memory ops outstanding (lgkm/exp not waited)
#define WAIT_VM(N) __builtin_amdgcn_s_waitcnt(0xF70 | (N))

__device__ inline unsigned short f2bf(float f) {
    unsigned u = __float_as_uint(f);
    u += 0x7fffu + ((u >> 16) & 1u);
    return (unsigned short)(u >> 16);
}

__device__ inline void gload16(const void* g, void* l) {
    __builtin_amdgcn_global_load_lds(
        (const __attribute__((address_space(1))) unsigned int*)g,
        (__attribute__((address_space(3))) unsigned int*)l, 16, 0, 0);
}

// ---------------- transpose + fp32->bf16 convert: in[K][N] -> out[N][K] ----------------
__global__ void transpose_convert(const float* __restrict__ in, unsigned short* __restrict__ out,
                                  int K, int N) {
    __shared__ float tile[32][33];
    const int n0 = blockIdx.x * 32, k0 = blockIdx.y * 32;
    const int tx = threadIdx.x, ty = threadIdx.y;  // 32 x 8
    for (int r = 0; r < 32; r += 8)
        tile[ty + r][tx] = in[(size_t)(k0 + ty + r) * N + n0 + tx];
    __syncthreads();
    for (int r = 0; r < 32; r += 8)
        out[(size_t)(n0 + ty + r) * K + k0 + tx] = f2bf(tile[tx][ty + r]);
}

// ---------------- V transpose: fp32 qkv-fused row -> bf16 (NKVH, D, S) ----------------
__global__ void transpose_v(const float* __restrict__ qkvf, unsigned short* __restrict__ vbt) {
    __shared__ float tile[32][33];
    const int s0 = blockIdx.x * 32, d0 = blockIdx.y * 32, hv = blockIdx.z;
    const int tx = threadIdx.x, ty = threadIdx.y;  // 32 x 8
    for (int r = 0; r < 32; r += 8)
        tile[ty + r][tx] = qkvf[(size_t)(s0 + ty + r) * QKVN + 5120 + hv * DHEAD + d0 + tx];
    __syncthreads();
    for (int r = 0; r < 32; r += 8)
        vbt[((size_t)hv * DHEAD + d0 + ty + r) * SEQ + s0 + tx] = f2bf(tile[tx][ty + r]);
}

// ---------------- LayerNorm: fp32 (S,H) -> bf16 (S,H) ----------------
__global__ __launch_bounds__(256) void layernorm_kernel(
    const float* __restrict__ hs, const float* __restrict__ w, const float* __restrict__ b,
    unsigned short* __restrict__ xb) {
    const int s = blockIdx.x;
    const float* row = hs + (size_t)s * HDIM;
    const int t = threadIdx.x;
    float vals[16];
    float sum = 0.f, sq = 0.f;
    for (int j = 0; j < 16; j++) {
        float v = row[j * 256 + t];
        vals[j] = v; sum += v; sq += v * v;
    }
    for (int off = 1; off < 64; off <<= 1) {
        sum += __shfl_xor(sum, off);
        sq  += __shfl_xor(sq, off);
    }
    __shared__ float ps[4], pq[4];
    if ((t & 63) == 0) { ps[t >> 6] = sum; pq[t >> 6] = sq; }
    __syncthreads();
    sum = ps[0] + ps[1] + ps[2] + ps[3];
    sq  = pq[0] + pq[1] + pq[2] + pq[3];
    const float mu = sum * (1.0f / HDIM);
    const float var = sq * (1.0f / HDIM) - mu * mu;
    const float rs = rsqrtf(var + 1e-5f);
    for (int j = 0; j < 16; j++) {
        int i = j * 256 + t;
        xb[(size_t)s * HDIM + i] = f2bf((vals[j] - mu) * rs * w[i] + b[i]);
    }
}

// ---------------- Big-tile pipelined GEMM: C = A[M,K] * Bt[N,K]^T (bf16 in, fp32 out) ----
// BM=BN=256, BK=32, 512 threads = 8 waves (2M x 4N), wave tile 128x64 (8x4 frags).
// Per wave K-tile: 12 ds_read_b128 : 32 MFMA -> MFMA-issue-bound (fixes 128^2's LDS bound).
// 3 LDS buffers (96KB), 2-tiles-ahead prefetch, boundary vmcnt(4), setprio, XOR swizzle.
// Optional split-K: gridInner blocks per slice; slice adds ksliceElems to A/Bt k-offset
// and cSliceStride to C.
__global__ __launch_bounds__(512, 2) void gemm256(
    const unsigned short* __restrict__ A, const unsigned short* __restrict__ Bt,
    float* __restrict__ C, int N, int lda, int Keff, int nbx,
    int gridInner, int ksliceElems, long long cSliceStride) {
    constexpr int BK = 32;
    __shared__ __align__(16) unsigned short Abuf[3][256 * BK];  // 48 KB
    __shared__ __align__(16) unsigned short Bbuf[3][256 * BK];  // 48 KB

    const int slice = blockIdx.x / gridInner;
    const int inner = blockIdx.x % gridInner;
    // XCD-chunked bijective swizzle (gridInner % 8 == 0)
    const int swz = (inner & 7) * (gridInner >> 3) + (inner >> 3);
    const int bx = swz % nbx, by = swz / nbx;
    const int row0 = by * 256, col0 = bx * 256;
    A  += (size_t)slice * ksliceElems;
    Bt += (size_t)slice * ksliceElems;
    C  += (size_t)slice * cSliceStride;

    const int t = threadIdx.x, lane = t & 63, w = t >> 6;
    const int wr = w >> 2, wc = w & 3;          // 2M x 4N wave grid
    const int r16 = lane & 15, kq = lane >> 4;

    // staging: srow = t>>2 in [0,128); two 128-row halves per matrix; chunk pre-swizzled
    const int srow = t >> 2;
    const int csw = (t & 3) ^ ((srow >> 1) & 3);
    const unsigned short* aga0 = A  + (size_t)(row0 + srow) * lda + csw * 8;
    const unsigned short* aga1 = A  + (size_t)(row0 + 128 + srow) * lda + csw * 8;
    const unsigned short* bga0 = Bt + (size_t)(col0 + srow) * lda + csw * 8;
    const unsigned short* bga1 = Bt + (size_t)(col0 + 128 + srow) * lda + csw * 8;
    // LDS dest: wave-uniform base + lane*16B (linear [row][chunk] layout)
    const int ldsA0 = w * 512, ldsA1 = 4096 + w * 512;

    const int NT = Keff / BK;

    // prologue: stage K-tiles 0 and 1 (4 loads each)
    gload16(aga0, &Abuf[0][ldsA0]);
    gload16(aga1, &Abuf[0][ldsA1]);
    gload16(bga0, &Bbuf[0][ldsA0]);
    gload16(bga1, &Bbuf[0][ldsA1]);
    gload16(aga0 + BK, &Abuf[1][ldsA0]);
    gload16(aga1 + BK, &Abuf[1][ldsA1]);
    gload16(bga0 + BK, &Bbuf[1][ldsA0]);
    gload16(bga1 + BK, &Bbuf[1][ldsA1]);
    WAIT_VM(4);  // K-tile 0 landed; K-tile 1's 4 in flight
    __builtin_amdgcn_s_barrier();

    f32x4 acc[8][4] = {};
    for (int kt = 0; kt < NT; ++kt) {
        const int cur = kt % 3, nx2 = (kt + 2) % 3;
        const bool pf = (kt + 2) < NT;
        const int koff = (kt + 2) * BK;
        const unsigned short* Ac = &Abuf[cur][0];
        const unsigned short* Bc = &Bbuf[cur][0];

        if (pf) {
            gload16(aga0 + koff, &Abuf[nx2][ldsA0]);
            gload16(aga1 + koff, &Abuf[nx2][ldsA1]);
        }
        bf16x8 af[8];
        #pragma unroll
        for (int i = 0; i < 8; i++) {
            int arow = wr * 128 + i * 16 + r16;
            af[i] = *(const bf16x8*)&Ac[arow * BK + (kq ^ ((arow >> 1) & 3)) * 8];
        }
        if (pf) {
            gload16(bga0 + koff, &Bbuf[nx2][ldsA0]);
            gload16(bga1 + koff, &Bbuf[nx2][ldsA1]);
        }
        bf16x8 bfr[4];
        #pragma unroll
        for (int j = 0; j < 4; j++) {
            int brow = wc * 64 + j * 16 + r16;
            bfr[j] = *(const bf16x8*)&Bc[brow * BK + (kq ^ ((brow >> 1) & 3)) * 8];
        }
        __builtin_amdgcn_s_setprio(1);
        #pragma unroll
        for (int i = 0; i < 8; i++)
            #pragma unroll
            for (int j = 0; j < 4; j++)
                acc[i][j] = __builtin_amdgcn_mfma_f32_16x16x32_bf16(af[i], bfr[j], acc[i][j], 0, 0, 0);
        __builtin_amdgcn_s_setprio(0);

        if (pf) WAIT_VM(4); else WAIT_VM(0);
        __builtin_amdgcn_s_barrier();
    }

    #pragma unroll
    for (int i = 0; i < 8; i++)
        #pragma unroll
        for (int j = 0; j < 4; j++)
            #pragma unroll
            for (int r = 0; r < 4; r++) {
                int row = row0 + wr * 128 + i * 16 + kq * 4 + r;
                int col = col0 + wc * 64 + j * 16 + r16;
                C[(size_t)row * N + col] = acc[i][j][r];
            }
}

// ---------------- split-K reduce: out = a + b ----------------
__global__ __launch_bounds__(256) void reduce_add(const float* __restrict__ a,
                                                  const float* __restrict__ b,
                                                  float* __restrict__ o, int n) {
    int i = (blockIdx.x * 256 + threadIdx.x) * 4;
    const int stride = gridDim.x * 256 * 4;
    for (; i < n; i += stride) {
        f32x4 x = *(const f32x4*)&a[i];
        f32x4 y = *(const f32x4*)&b[i];
        x += y;
        *(f32x4*)&o[i] = x;
    }
}

// ---------------- RoPE + convert to head-major bf16 (reads fused qkv fp32) ----------------
__global__ void rope_convert(const float* __restrict__ qkvf,
                             unsigned short* __restrict__ qb, unsigned short* __restrict__ kb) {
    const int s = blockIdx.x;
    const int head = blockIdx.y;
    const int d = threadIdx.x;  // 0..63
    const float SCALE = 0.08838834764831845f;  // 1/sqrt(128)
    const float NLOG = -0.14391156831212787f;  // -ln(10000)/64
    float f = (float)s * __expf((float)d * NLOG);
    float sn, c;
    __sincosf(f, &sn, &c);
    if (head < NQH) {
        const float* src = qkvf + (size_t)s * QKVN + head * DHEAD;
        float x1 = src[d], x2 = src[d + 64];
        unsigned short* dst = qb + ((size_t)head * SEQ + s) * DHEAD;
        dst[d]      = f2bf((x1 * c - x2 * sn) * SCALE);
        dst[d + 64] = f2bf((x2 * c + x1 * sn) * SCALE);
    } else {
        const int hk = head - NQH;
        const float* src = qkvf + (size_t)s * QKVN + 4096 + hk * DHEAD;
        float x1 = src[d], x2 = src[d + 64];
        unsigned short* dst = kb + ((size_t)hk * SEQ + s) * DHEAD;
        dst[d]      = f2bf(x1 * c - x2 * sn);
        dst[d + 64] = f2bf(x2 * c + x1 * sn);
    }
}

// ---------------- Flash attention ----------------
// T14 async-STAGE split: K/V global->reg loads for tile kb+1 issued before compute of kb,
// ds_writes happen after the barrier at the top of iteration kb+1.
__global__ __launch_bounds__(256) void attention_kernel(
    const unsigned short* __restrict__ Q, const unsigned short* __restrict__ K,
    const unsigned short* __restrict__ Vt, unsigned short* __restrict__ O) {
    __shared__ __align__(16) unsigned short Ks[64 * 128];    // [kcol][d], swizzled
    __shared__ __align__(16) unsigned short Vs[128 * 64];    // [d][k], swizzled
    __shared__ __align__(16) unsigned short Pl[4][16 * 64];  // per-wave [qr][k], swizzled
    const int h = blockIdx.x & 31;
    const int qb = (SEQ / 64 - 1) - (blockIdx.x >> 5);  // LPT: longest blocks first
    const int t = threadIdx.x, lane = t & 63, wave = t >> 6;
    const int r16 = lane & 15, kq = lane >> 4;
    const int q0 = qb * 64 + wave * 16;
    const int hkv = h >> 2;

    bf16x8 qfrag[4];
    const unsigned short* qrow = Q + ((size_t)h * SEQ + q0 + r16) * DHEAD;
    for (int c = 0; c < 4; c++) qfrag[c] = *(const bf16x8*)&qrow[c * 32 + kq * 8];

    f32x4 acc[8] = {};
    float m_r[4], l_r[4];
    for (int r = 0; r < 4; r++) { m_r[r] = -1e30f; l_r[r] = 0.f; }

    const unsigned short* Kg = K + (size_t)hkv * SEQ * DHEAD;
    const unsigned short* Vg = Vt + (size_t)hkv * DHEAD * SEQ;
    unsigned short* pw = &Pl[wave][0];

    const int krow = t >> 4, kch = t & 15;   // K staging: 4 rows/iter via +64
    const int vrow = t >> 3, vch = t & 7;    // V staging: 32 d-rows/iter via +32

    ushort8 kreg[4], vreg[4];
    #pragma unroll
    for (int p = 0; p < 4; p++) {
        kreg[p] = *(const ushort8*)&Kg[(size_t)(p * 16 + krow) * DHEAD + kch * 8];
        vreg[p] = *(const ushort8*)&Vg[(size_t)(p * 32 + vrow) * SEQ + vch * 8];
    }

    for (int kb = 0; kb <= qb; ++kb) {
        __syncthreads();
        #pragma unroll
        for (int p = 0; p < 4; p++) {
            int row = p * 16 + krow;
            *(ushort8*)&Ks[row * 128 + ((kch ^ (row & 7)) * 8)] = kreg[p];
            int vr = p * 32 + vrow;
            *(ushort8*)&Vs[vr * 64 + ((vch ^ (vr & 7)) * 8)] = vreg[p];
        }
        if (kb < qb) {
            #pragma unroll
            for (int p = 0; p < 4; p++) {
                kreg[p] = *(const ushort8*)&Kg[(size_t)((kb + 1) * 64 + p * 16 + krow) * DHEAD + kch * 8];
                vreg[p] = *(const ushort8*)&Vg[(size_t)(p * 32 + vrow) * SEQ + (kb + 1) * 64 + vch * 8];
            }
        }
        __syncthreads();
        f32x4 sf[4];
        for (int ct = 0; ct < 4; ct++) {
            f32x4 s4 = {};
            int row = ct * 16 + r16;
            for (int c = 0; c < 4; c++) {
                int ch = (c * 4 + kq) ^ (row & 7);
                bf16x8 kf2 = *(const bf16x8*)&Ks[row * 128 + ch * 8];
                s4 = __builtin_amdgcn_mfma_f32_16x16x32_bf16(qfrag[c], kf2, s4, 0, 0, 0);
            }
            sf[ct] = s4;
        }
        if (kb == qb) {
            for (int r = 0; r < 4; r++) {
                int qg = q0 + kq * 4 + r;
                for (int ct = 0; ct < 4; ct++) {
                    int col = kb * 64 + ct * 16 + r16;
                    if (col > qg) sf[ct][r] = -1e30f;
                }
            }
        }
        for (int r = 0; r < 4; r++) {
            float mx = fmaxf(fmaxf(sf[0][r], sf[1][r]), fmaxf(sf[2][r], sf[3][r]));
            for (int off = 1; off < 16; off <<= 1) mx = fmaxf(mx, __shfl_xor(mx, off, 16));
            float mnew = fmaxf(m_r[r], mx);
            float scale = __expf(m_r[r] - mnew);
            float sum = 0.f;
            for (int ct = 0; ct < 4; ct++) {
                float p = __expf(sf[ct][r] - mnew);
                sf[ct][r] = p; sum += p;
            }
            for (int off = 1; off < 16; off <<= 1) sum += __shfl_xor(sum, off, 16);
            l_r[r] = l_r[r] * scale + sum;
            m_r[r] = mnew;
            for (int nt = 0; nt < 8; nt++) acc[nt][r] *= scale;
        }
        for (int ct = 0; ct < 4; ct++)
            for (int r = 0; r < 4; r++) {
                int prow = kq * 4 + r, col = ct * 16 + r16;
                int ch = (col >> 3) ^ (prow & 7);
                pw[prow * 64 + ch * 8 + (col & 7)] = f2bf(sf[ct][r]);
            }
        for (int k32 = 0; k32 < 2; k32++) {
            int pch = (k32 * 4 + kq) ^ (r16 & 7);
            bf16x8 pf = *(const bf16x8*)&pw[r16 * 64 + pch * 8];
            for (int nt = 0; nt < 8; nt++) {
                int vr2 = nt * 16 + r16;
                int vc2 = (k32 * 4 + kq) ^ (vr2 & 7);
                bf16x8 vfr = *(const bf16x8*)&Vs[vr2 * 64 + vc2 * 8];
                acc[nt] = __builtin_amdgcn_mfma_f32_16x16x32_bf16(pf, vfr, acc[nt], 0, 0, 0);
            }
        }
    }
    float invl[4];
    for (int r = 0; r < 4; r++) invl[r] = 1.0f / l_r[r];
    for (int nt = 0; nt < 8; nt++)
        for (int r = 0; r < 4; r++)
            O[(size_t)(q0 + kq * 4 + r) * HDIM + h * DHEAD + nt * 16 + r16] =
                f2bf(acc[nt][r] * invl[r]);
}

extern "C" void kernel_launch(void* const* d_in, const int* in_sizes, int n_in,
                              void* d_out, int out_size, void* d_ws, size_t ws_size,
                              hipStream_t stream) {
    const float* hs  = (const float*)d_in[0];
    const float* lnw = (const float*)d_in[1];
    const float* lnb = (const float*)d_in[2];
    const float* wq  = (const float*)d_in[3];
    const float* wk  = (const float*)d_in[4];
    const float* wv  = (const float*)d_in[5];
    const float* wo  = (const float*)d_in[6];
    float* out = (float*)d_out;

    char* ws = (char*)d_ws;
    size_t off = 0;
    auto alloc = [&](size_t bytes) {
        void* p = ws + off;
        off += (bytes + 255) & ~(size_t)255;
        return p;
    };
    unsigned short* xb   = (unsigned short*)alloc((size_t)SEQ * HDIM * 2);
    // wqT/wkT/wvT contiguous -> fused [6144][4096] B matrix
    unsigned short* wqT  = (unsigned short*)alloc((size_t)HDIM * (NQH * DHEAD) * 2);
    unsigned short* wkT  = (unsigned short*)alloc((size_t)HDIM * (NKVH * DHEAD) * 2);
    unsigned short* wvT  = (unsigned short*)alloc((size_t)HDIM * (NKVH * DHEAD) * 2);
    unsigned short* woT  = (unsigned short*)alloc((size_t)(NQH * DHEAD) * HDIM * 2);
    float* qkvf          = (float*)alloc((size_t)SEQ * QKVN * 4);
    unsigned short* qbuf = (unsigned short*)alloc((size_t)NQH * SEQ * DHEAD * 2);
    unsigned short* kbuf = (unsigned short*)alloc((size_t)NKVH * SEQ * DHEAD * 2);
    unsigned short* vbt  = (unsigned short*)alloc((size_t)NKVH * DHEAD * SEQ * 2);
    unsigned short* attnb = (unsigned short*)qkvf;  // reuse fused-fp32 region after rope/v-transpose
    // split-K partials for O-proj: 64 MiB, overlays xb+wqT+wkT+wvT (dead after QKV gemm)
    float* cpart = (float*)xb;

    dim3 tb(32, 8);
    transpose_convert<<<dim3(4096 / 32, 4096 / 32), tb, 0, stream>>>(wq, wqT, 4096, 4096);
    transpose_convert<<<dim3(1024 / 32, 4096 / 32), tb, 0, stream>>>(wk, wkT, 4096, 1024);
    transpose_convert<<<dim3(1024 / 32, 4096 / 32), tb, 0, stream>>>(wv, wvT, 4096, 1024);
    transpose_convert<<<dim3(4096 / 32, 4096 / 32), tb, 0, stream>>>(wo, woT, 4096, 4096);

    layernorm_kernel<<<SEQ, 256, 0, stream>>>(hs, lnw, lnb, xb);

    // fused QKV projection: [2048][4096] x [6144][4096]^T -> [2048][6144]
    gemm256<<<(2048 / 256) * (QKVN / 256), 512, 0, stream>>>(
        xb, wqT, qkvf, QKVN, 4096, 4096, QKVN / 256, (2048 / 256) * (QKVN / 256), 0, 0);

    rope_convert<<<dim3(SEQ, NQH + NKVH), 64, 0, stream>>>(qkvf, qbuf, kbuf);
    transpose_v<<<dim3(SEQ / 32, DHEAD / 32, NKVH), tb, 0, stream>>>(qkvf, vbt);

    attention_kernel<<<NQH * (SEQ / 64), 256, 0, stream>>>(qbuf, kbuf, vbt, attnb);

    // O-proj with split-K=2: grid 256 = 2 slices x 128 blocks, K=2048 each
    gemm256<<<2 * (2048 / 256) * (4096 / 256), 512, 0, stream>>>(
        attnb, woT, cpart, 4096, 4096, 2048, 4096 / 256,
        (2048 / 256) * (4096 / 256), 2048, (long long)2048 * 4096);
    reduce_add<<<2048, 256, 0, stream>>>(cpart, cpart + (size_t)2048 * 4096, out,
                                         2048 * 4096);
}

// Round 6
// 377.200 us; speedup vs baseline: 1.1927x; 1.1927x over previous
//
#include <hip/hip_runtime.h>
#include <hip/hip_bf16.h>

#define HDIM 4096
#define DHEAD 128
#define NQH 32
#define NKVH 8
#define SEQ 2048
#define QKVN 6144  // fused N = 4096 + 1024 + 1024

typedef __bf16 bf16x8 __attribute__((ext_vector_type(8)));
typedef unsigned short ushort8 __attribute__((ext_vector_type(8)));
typedef float f32x4 __attribute__((ext_vector_type(4)));

// wait until <= N vector-memory ops outstanding (lgkm/exp not waited)
#define WAIT_VM(N) __builtin_amdgcn_s_waitcnt(0xF70 | (N))

__device__ inline unsigned short f2bf(float f) {
    unsigned u = __float_as_uint(f);
    u += 0x7fffu + ((u >> 16) & 1u);
    return (unsigned short)(u >> 16);
}

__device__ inline void gload16(const void* g, void* l) {
    __builtin_amdgcn_global_load_lds(
        (const __attribute__((address_space(1))) unsigned int*)g,
        (__attribute__((address_space(3))) unsigned int*)l, 16, 0, 0);
}

// ---------------- transpose + fp32->bf16 convert: in[K][N] -> out[N][K] ----------------
__global__ void transpose_convert(const float* __restrict__ in, unsigned short* __restrict__ out,
                                  int K, int N) {
    __shared__ float tile[32][33];
    const int n0 = blockIdx.x * 32, k0 = blockIdx.y * 32;
    const int tx = threadIdx.x, ty = threadIdx.y;  // 32 x 8
    for (int r = 0; r < 32; r += 8)
        tile[ty + r][tx] = in[(size_t)(k0 + ty + r) * N + n0 + tx];
    __syncthreads();
    for (int r = 0; r < 32; r += 8)
        out[(size_t)(n0 + ty + r) * K + k0 + tx] = f2bf(tile[tx][ty + r]);
}

// ---------------- V transpose: fp32 qkv-fused row -> bf16 (NKVH, D, S) ----------------
__global__ void transpose_v(const float* __restrict__ qkvf, unsigned short* __restrict__ vbt) {
    __shared__ float tile[32][33];
    const int s0 = blockIdx.x * 32, d0 = blockIdx.y * 32, hv = blockIdx.z;
    const int tx = threadIdx.x, ty = threadIdx.y;  // 32 x 8
    for (int r = 0; r < 32; r += 8)
        tile[ty + r][tx] = qkvf[(size_t)(s0 + ty + r) * QKVN + 5120 + hv * DHEAD + d0 + tx];
    __syncthreads();
    for (int r = 0; r < 32; r += 8)
        vbt[((size_t)hv * DHEAD + d0 + ty + r) * SEQ + s0 + tx] = f2bf(tile[tx][ty + r]);
}

// ---------------- LayerNorm: fp32 (S,H) -> bf16 (S,H) ----------------
__global__ __launch_bounds__(256) void layernorm_kernel(
    const float* __restrict__ hs, const float* __restrict__ w, const float* __restrict__ b,
    unsigned short* __restrict__ xb) {
    const int s = blockIdx.x;
    const float* row = hs + (size_t)s * HDIM;
    const int t = threadIdx.x;
    float vals[16];
    float sum = 0.f, sq = 0.f;
    for (int j = 0; j < 16; j++) {
        float v = row[j * 256 + t];
        vals[j] = v; sum += v; sq += v * v;
    }
    for (int off = 1; off < 64; off <<= 1) {
        sum += __shfl_xor(sum, off);
        sq  += __shfl_xor(sq, off);
    }
    __shared__ float ps[4], pq[4];
    if ((t & 63) == 0) { ps[t >> 6] = sum; pq[t >> 6] = sq; }
    __syncthreads();
    sum = ps[0] + ps[1] + ps[2] + ps[3];
    sq  = pq[0] + pq[1] + pq[2] + pq[3];
    const float mu = sum * (1.0f / HDIM);
    const float var = sq * (1.0f / HDIM) - mu * mu;
    const float rs = rsqrtf(var + 1e-5f);
    for (int j = 0; j < 16; j++) {
        int i = j * 256 + t;
        xb[(size_t)s * HDIM + i] = f2bf((vals[j] - mu) * rs * w[i] + b[i]);
    }
}

// ---------------- 8-phase pipelined GEMM: C = A[M,K] * Bt[N,K]^T (bf16 in, fp32 out) ----
// BM=BN=256, BK=64, 512 thr = 8 waves (2M x 4N), wave tile 128x64.
// LDS: 2 buffers x 2 kh-quadrants x [256][32] per matrix = 128 KB.
// 4 phases per K-tile, each: {ds_read one (ih,kh) quadrant's frags | stage 1 quadrant
// of tile t+1 (2 gloads) | setprio 16-MFMA}. Gates every 2 phases: vmcnt(4)+s_barrier
// (counted: 2 quadrants always in flight; tail drains with vmcnt(0)).
// Ledger (loads/thread): each gate has 8 outstanding; vmcnt(4) lands the 2 quadrants
// the next 2 phases read. Stages always target the dead buffer -> race-free.
__global__ __launch_bounds__(512, 2) void gemm8p(
    const unsigned short* __restrict__ A, const unsigned short* __restrict__ Bt,
    float* __restrict__ C, int N, int lda, int Keff, int nbx,
    int gridInner, int ksliceElems, long long cSliceStride) {
    __shared__ __align__(16) unsigned short Abuf[2 * 2 * 256 * 32];  // 64 KB
    __shared__ __align__(16) unsigned short Bbuf[2 * 2 * 256 * 32];  // 64 KB

    const int slice = blockIdx.x / gridInner;
    const int inner = blockIdx.x % gridInner;
    // XCD-chunked bijective swizzle (gridInner % 8 == 0)
    const int swz = (inner & 7) * (gridInner >> 3) + (inner >> 3);
    const int bx = swz % nbx, by = swz / nbx;
    const int row0 = by * 256, col0 = bx * 256;
    A  += (size_t)slice * ksliceElems;
    Bt += (size_t)slice * ksliceElems;
    C  += (size_t)slice * cSliceStride;

    const int t = threadIdx.x, lane = t & 63, w = t >> 6;
    const int wr = w >> 2, wc = w & 3;          // 2M x 4N wave grid
    const int r16 = lane & 15, kq = lane >> 4;

    // staging: thread t covers rows srow and 128+srow, chunk (t&3) pre-swizzled.
    // ((128+srow)>>1)&3 == ((srow>>1)&3) so both rows share the swizzled chunk.
    const int srow = t >> 2;
    const int scsw = (t & 3) ^ ((srow >> 1) & 3);
    const unsigned short* aStage = A  + (size_t)(row0 + srow) * lda + scsw * 8;
    const unsigned short* bStage = Bt + (size_t)(col0 + srow) * lda + scsw * 8;
    const size_t half = 128 * (size_t)lda;
    const int wdst = w * 512;  // wave-uniform LDS dest base (elements)

    const int NT = Keff / 64;

#define STAGE(p0, ldsbuf, bufidx, kh, kt) do {                                  \
        const unsigned short* _g = (p0) + (size_t)(kt) * 64 + (kh) * 32;        \
        gload16(_g,        &ldsbuf[((bufidx) * 2 + (kh)) * 8192 + wdst]);       \
        gload16(_g + half, &ldsbuf[((bufidx) * 2 + (kh)) * 8192 + 4096 + wdst]);\
    } while (0)

#define LDA4(dst, bufidx, kh, ih) {                                             \
        _Pragma("unroll") for (int i = 0; i < 4; i++) {                         \
            int arow = wr * 128 + (ih) * 64 + i * 16 + r16;                     \
            dst[i] = *(const bf16x8*)&Abuf[((bufidx) * 2 + (kh)) * 8192 +       \
                     arow * 32 + (kq ^ ((arow >> 1) & 3)) * 8];                 \
        } }

#define LDB4(dst, bufidx, kh) {                                                 \
        _Pragma("unroll") for (int j = 0; j < 4; j++) {                         \
            int brow = wc * 64 + j * 16 + r16;                                  \
            dst[j] = *(const bf16x8*)&Bbuf[((bufidx) * 2 + (kh)) * 8192 +       \
                     brow * 32 + (kq ^ ((brow >> 1) & 3)) * 8];                 \
        } }

#define MM16(ih, av, bv) {                                                      \
        __builtin_amdgcn_s_setprio(1);                                          \
        _Pragma("unroll") for (int i = 0; i < 4; i++)                           \
            _Pragma("unroll") for (int j = 0; j < 4; j++)                       \
                acc[(ih) * 4 + i][j] = __builtin_amdgcn_mfma_f32_16x16x32_bf16( \
                    av[i], bv[j], acc[(ih) * 4 + i][j], 0, 0, 0);               \
        __builtin_amdgcn_s_setprio(0); }

    // prologue: stage all 4 quadrants of K-tile 0 (issue order = loop order)
    STAGE(aStage, Abuf, 0, 0, 0);
    STAGE(bStage, Bbuf, 0, 0, 0);
    STAGE(aStage, Abuf, 0, 1, 0);
    STAGE(bStage, Bbuf, 0, 1, 0);
    WAIT_VM(4);  // A-kh0, B-kh0 landed; kh1 quadrants in flight
    __builtin_amdgcn_s_barrier();

    f32x4 acc[8][4] = {};
    for (int kt = 0; kt < NT; ++kt) {
        const int cur = kt & 1, nxt = cur ^ 1;
        const bool nl = (kt + 1 < NT);
        bf16x8 a0[4], a1[4], bv[4];
        // ph0: quadrant (ih0, kh0); stage A-kh0(t+1)
        LDA4(a0, cur, 0, 0);
        LDB4(bv, cur, 0);
        if (nl) STAGE(aStage, Abuf, nxt, 0, kt + 1);
        MM16(0, a0, bv);
        // ph1: (ih1, kh0), B reused; stage B-kh0(t+1); mid-gate
        LDA4(a1, cur, 0, 1);
        if (nl) STAGE(bStage, Bbuf, nxt, 0, kt + 1);
        MM16(1, a1, bv);
        if (nl) WAIT_VM(4); else WAIT_VM(0);  // A-kh1,B-kh1 of THIS tile landed
        __builtin_amdgcn_s_barrier();
        // ph2: (ih0, kh1); stage A-kh1(t+1)
        LDA4(a0, cur, 1, 0);
        LDB4(bv, cur, 1);
        if (nl) STAGE(aStage, Abuf, nxt, 1, kt + 1);
        MM16(0, a0, bv);
        // ph3: (ih1, kh1); stage B-kh1(t+1); boundary gate
        LDA4(a1, cur, 1, 1);
        if (nl) STAGE(bStage, Bbuf, nxt, 1, kt + 1);
        MM16(1, a1, bv);
        if (nl) {
            WAIT_VM(4);  // A-kh0,B-kh0 of NEXT tile landed; its kh1 in flight
            __builtin_amdgcn_s_barrier();
        }
    }

    #pragma unroll
    for (int i = 0; i < 8; i++)
        #pragma unroll
        for (int j = 0; j < 4; j++)
            #pragma unroll
            for (int r = 0; r < 4; r++) {
                int row = row0 + wr * 128 + i * 16 + kq * 4 + r;
                int col = col0 + wc * 64 + j * 16 + r16;
                C[(size_t)row * N + col] = acc[i][j][r];
            }
#undef STAGE
#undef LDA4
#undef LDB4
#undef MM16
}

// ---------------- split-K reduce: out = a + b ----------------
__global__ __launch_bounds__(256) void reduce_add(const float* __restrict__ a,
                                                  const float* __restrict__ b,
                                                  float* __restrict__ o, int n) {
    int i = (blockIdx.x * 256 + threadIdx.x) * 4;
    const int stride = gridDim.x * 256 * 4;
    for (; i < n; i += stride) {
        f32x4 x = *(const f32x4*)&a[i];
        f32x4 y = *(const f32x4*)&b[i];
        x += y;
        *(f32x4*)&o[i] = x;
    }
}

// ---------------- RoPE + convert to head-major bf16 (reads fused qkv fp32) ----------------
__global__ void rope_convert(const float* __restrict__ qkvf,
                             unsigned short* __restrict__ qb, unsigned short* __restrict__ kb) {
    const int s = blockIdx.x;
    const int head = blockIdx.y;
    const int d = threadIdx.x;  // 0..63
    const float SCALE = 0.08838834764831845f;  // 1/sqrt(128)
    const float NLOG = -0.14391156831212787f;  // -ln(10000)/64
    float f = (float)s * __expf((float)d * NLOG);
    float sn, c;
    __sincosf(f, &sn, &c);
    if (head < NQH) {
        const float* src = qkvf + (size_t)s * QKVN + head * DHEAD;
        float x1 = src[d], x2 = src[d + 64];
        unsigned short* dst = qb + ((size_t)head * SEQ + s) * DHEAD;
        dst[d]      = f2bf((x1 * c - x2 * sn) * SCALE);
        dst[d + 64] = f2bf((x2 * c + x1 * sn) * SCALE);
    } else {
        const int hk = head - NQH;
        const float* src = qkvf + (size_t)s * QKVN + 4096 + hk * DHEAD;
        float x1 = src[d], x2 = src[d + 64];
        unsigned short* dst = kb + ((size_t)hk * SEQ + s) * DHEAD;
        dst[d]      = f2bf(x1 * c - x2 * sn);
        dst[d + 64] = f2bf(x2 * c + x1 * sn);
    }
}

// ---------------- Flash attention ----------------
// T14 async-STAGE split: K/V global->reg loads for tile kb+1 issued before compute of kb,
// ds_writes happen after the barrier at the top of iteration kb+1.
__global__ __launch_bounds__(256) void attention_kernel(
    const unsigned short* __restrict__ Q, const unsigned short* __restrict__ K,
    const unsigned short* __restrict__ Vt, unsigned short* __restrict__ O) {
    __shared__ __align__(16) unsigned short Ks[64 * 128];    // [kcol][d], swizzled
    __shared__ __align__(16) unsigned short Vs[128 * 64];    // [d][k], swizzled
    __shared__ __align__(16) unsigned short Pl[4][16 * 64];  // per-wave [qr][k], swizzled
    const int h = blockIdx.x & 31;
    const int qb = (SEQ / 64 - 1) - (blockIdx.x >> 5);  // LPT: longest blocks first
    const int t = threadIdx.x, lane = t & 63, wave = t >> 6;
    const int r16 = lane & 15, kq = lane >> 4;
    const int q0 = qb * 64 + wave * 16;
    const int hkv = h >> 2;

    bf16x8 qfrag[4];
    const unsigned short* qrow = Q + ((size_t)h * SEQ + q0 + r16) * DHEAD;
    for (int c = 0; c < 4; c++) qfrag[c] = *(const bf16x8*)&qrow[c * 32 + kq * 8];

    f32x4 acc[8] = {};
    float m_r[4], l_r[4];
    for (int r = 0; r < 4; r++) { m_r[r] = -1e30f; l_r[r] = 0.f; }

    const unsigned short* Kg = K + (size_t)hkv * SEQ * DHEAD;
    const unsigned short* Vg = Vt + (size_t)hkv * DHEAD * SEQ;
    unsigned short* pw = &Pl[wave][0];

    const int krow = t >> 4, kch = t & 15;   // K staging: 4 rows/iter via +64
    const int vrow = t >> 3, vch = t & 7;    // V staging: 32 d-rows/iter via +32

    ushort8 kreg[4], vreg[4];
    #pragma unroll
    for (int p = 0; p < 4; p++) {
        kreg[p] = *(const ushort8*)&Kg[(size_t)(p * 16 + krow) * DHEAD + kch * 8];
        vreg[p] = *(const ushort8*)&Vg[(size_t)(p * 32 + vrow) * SEQ + vch * 8];
    }

    for (int kb = 0; kb <= qb; ++kb) {
        __syncthreads();
        #pragma unroll
        for (int p = 0; p < 4; p++) {
            int row = p * 16 + krow;
            *(ushort8*)&Ks[row * 128 + ((kch ^ (row & 7)) * 8)] = kreg[p];
            int vr = p * 32 + vrow;
            *(ushort8*)&Vs[vr * 64 + ((vch ^ (vr & 7)) * 8)] = vreg[p];
        }
        if (kb < qb) {
            #pragma unroll
            for (int p = 0; p < 4; p++) {
                kreg[p] = *(const ushort8*)&Kg[(size_t)((kb + 1) * 64 + p * 16 + krow) * DHEAD + kch * 8];
                vreg[p] = *(const ushort8*)&Vg[(size_t)(p * 32 + vrow) * SEQ + (kb + 1) * 64 + vch * 8];
            }
        }
        __syncthreads();
        f32x4 sf[4];
        for (int ct = 0; ct < 4; ct++) {
            f32x4 s4 = {};
            int row = ct * 16 + r16;
            for (int c = 0; c < 4; c++) {
                int ch = (c * 4 + kq) ^ (row & 7);
                bf16x8 kf2 = *(const bf16x8*)&Ks[row * 128 + ch * 8];
                s4 = __builtin_amdgcn_mfma_f32_16x16x32_bf16(qfrag[c], kf2, s4, 0, 0, 0);
            }
            sf[ct] = s4;
        }
        if (kb == qb) {
            for (int r = 0; r < 4; r++) {
                int qg = q0 + kq * 4 + r;
                for (int ct = 0; ct < 4; ct++) {
                    int col = kb * 64 + ct * 16 + r16;
                    if (col > qg) sf[ct][r] = -1e30f;
                }
            }
        }
        for (int r = 0; r < 4; r++) {
            float mx = fmaxf(fmaxf(sf[0][r], sf[1][r]), fmaxf(sf[2][r], sf[3][r]));
            for (int off = 1; off < 16; off <<= 1) mx = fmaxf(mx, __shfl_xor(mx, off, 16));
            float mnew = fmaxf(m_r[r], mx);
            float scale = __expf(m_r[r] - mnew);
            float sum = 0.f;
            for (int ct = 0; ct < 4; ct++) {
                float p = __expf(sf[ct][r] - mnew);
                sf[ct][r] = p; sum += p;
            }
            for (int off = 1; off < 16; off <<= 1) sum += __shfl_xor(sum, off, 16);
            l_r[r] = l_r[r] * scale + sum;
            m_r[r] = mnew;
            for (int nt = 0; nt < 8; nt++) acc[nt][r] *= scale;
        }
        for (int ct = 0; ct < 4; ct++)
            for (int r = 0; r < 4; r++) {
                int prow = kq * 4 + r, col = ct * 16 + r16;
                int ch = (col >> 3) ^ (prow & 7);
                pw[prow * 64 + ch * 8 + (col & 7)] = f2bf(sf[ct][r]);
            }
        for (int k32 = 0; k32 < 2; k32++) {
            int pch = (k32 * 4 + kq) ^ (r16 & 7);
            bf16x8 pf = *(const bf16x8*)&pw[r16 * 64 + pch * 8];
            for (int nt = 0; nt < 8; nt++) {
                int vr2 = nt * 16 + r16;
                int vc2 = (k32 * 4 + kq) ^ (vr2 & 7);
                bf16x8 vfr = *(const bf16x8*)&Vs[vr2 * 64 + vc2 * 8];
                acc[nt] = __builtin_amdgcn_mfma_f32_16x16x32_bf16(pf, vfr, acc[nt], 0, 0, 0);
            }
        }
    }
    float invl[4];
    for (int r = 0; r < 4; r++) invl[r] = 1.0f / l_r[r];
    for (int nt = 0; nt < 8; nt++)
        for (int r = 0; r < 4; r++)
            O[(size_t)(q0 + kq * 4 + r) * HDIM + h * DHEAD + nt * 16 + r16] =
                f2bf(acc[nt][r] * invl[r]);
}

extern "C" void kernel_launch(void* const* d_in, const int* in_sizes, int n_in,
                              void* d_out, int out_size, void* d_ws, size_t ws_size,
                              hipStream_t stream) {
    const float* hs  = (const float*)d_in[0];
    const float* lnw = (const float*)d_in[1];
    const float* lnb = (const float*)d_in[2];
    const float* wq  = (const float*)d_in[3];
    const float* wk  = (const float*)d_in[4];
    const float* wv  = (const float*)d_in[5];
    const float* wo  = (const float*)d_in[6];
    float* out = (float*)d_out;

    char* ws = (char*)d_ws;
    size_t off = 0;
    auto alloc = [&](size_t bytes) {
        void* p = ws + off;
        off += (bytes + 255) & ~(size_t)255;
        return p;
    };
    unsigned short* xb   = (unsigned short*)alloc((size_t)SEQ * HDIM * 2);
    // wqT/wkT/wvT contiguous -> fused [6144][4096] B matrix
    unsigned short* wqT  = (unsigned short*)alloc((size_t)HDIM * (NQH * DHEAD) * 2);
    unsigned short* wkT  = (unsigned short*)alloc((size_t)HDIM * (NKVH * DHEAD) * 2);
    unsigned short* wvT  = (unsigned short*)alloc((size_t)HDIM * (NKVH * DHEAD) * 2);
    unsigned short* woT  = (unsigned short*)alloc((size_t)(NQH * DHEAD) * HDIM * 2);
    float* qkvf          = (float*)alloc((size_t)SEQ * QKVN * 4);
    unsigned short* qbuf = (unsigned short*)alloc((size_t)NQH * SEQ * DHEAD * 2);
    unsigned short* kbuf = (unsigned short*)alloc((size_t)NKVH * SEQ * DHEAD * 2);
    unsigned short* vbt  = (unsigned short*)alloc((size_t)NKVH * DHEAD * SEQ * 2);
    unsigned short* attnb = (unsigned short*)qkvf;  // reuse fused-fp32 region after rope/v-transpose
    // split-K partials for O-proj: exactly 64 MiB, overlays xb+wqT+wkT+wvT (dead by then)
    float* cpart = (float*)xb;

    dim3 tb(32, 8);
    transpose_convert<<<dim3(4096 / 32, 4096 / 32), tb, 0, stream>>>(wq, wqT, 4096, 4096);
    transpose_convert<<<dim3(1024 / 32, 4096 / 32), tb, 0, stream>>>(wk, wkT, 4096, 1024);
    transpose_convert<<<dim3(1024 / 32, 4096 / 32), tb, 0, stream>>>(wv, wvT, 4096, 1024);
    transpose_convert<<<dim3(4096 / 32, 4096 / 32), tb, 0, stream>>>(wo, woT, 4096, 4096);

    layernorm_kernel<<<SEQ, 256, 0, stream>>>(hs, lnw, lnb, xb);

    // fused QKV projection: [2048][4096] x [6144][4096]^T -> [2048][6144]
    gemm8p<<<(2048 / 256) * (QKVN / 256), 512, 0, stream>>>(
        xb, wqT, qkvf, QKVN, 4096, 4096, QKVN / 256, (2048 / 256) * (QKVN / 256), 0, 0);

    rope_convert<<<dim3(SEQ, NQH + NKVH), 64, 0, stream>>>(qkvf, qbuf, kbuf);
    transpose_v<<<dim3(SEQ / 32, DHEAD / 32, NKVH), tb, 0, stream>>>(qkvf, vbt);

    attention_kernel<<<NQH * (SEQ / 64), 256, 0, stream>>>(qbuf, kbuf, vbt, attnb);

    // O-proj with split-K=2: grid 256 = 2 slices x 128 blocks, K=2048 each
    gemm8p<<<2 * (2048 / 256) * (4096 / 256), 512, 0, stream>>>(
        attnb, woT, cpart, 4096, 4096, 2048, 4096 / 256,
        (2048 / 256) * (4096 / 256), 2048, (long long)2048 * 4096);
    reduce_add<<<2048, 256, 0, stream>>>(cpart, cpart + (size_t)2048 * 4096, out,
                                         2048 * 4096);
}